// Round 12
// baseline (138.296 us; speedup 1.0000x reference)
//
#include <hip/hip_runtime.h>
#include <hip/hip_bf16.h>

// B=4, S=1024, D=1024, H=16, HD=64
#define BB 4
#define SS 1024
#define DD 1024
#define HH 16
#define HD 64
#define MM (BB * SS)
#define LN_EPS 1e-12f

typedef unsigned short u16;
typedef unsigned int u32;
typedef __attribute__((ext_vector_type(8))) short bf16x8;
typedef __attribute__((ext_vector_type(4))) float f32x4;
typedef __attribute__((ext_vector_type(4))) unsigned short u16x4;
typedef __attribute__((ext_vector_type(8))) unsigned short u16x8;

// ---- helpers ---------------------------------------------------------------
__device__ __forceinline__ u16 f2bf(float f) {          // compiler-native RNE cast
    __hip_bfloat16 h = __float2bfloat16(f);
    u16 r; __builtin_memcpy(&r, &h, 2); return r;
}
__device__ __forceinline__ float bf2f(u16 u) {
    unsigned v = ((unsigned)u) << 16;
    float f; __builtin_memcpy(&f, &v, 4); return f;
}

typedef const __attribute__((address_space(1))) unsigned int* gas1_t;
typedef __attribute__((address_space(3))) unsigned int* las3_t;
__device__ __forceinline__ void gload16(const void* g, void* s) {
    __builtin_amdgcn_global_load_lds((gas1_t)g, (las3_t)s, 16, 0, 0);
}

// counted vmem waits (raw; never full-drain in steady state)
__device__ __forceinline__ void vmw0() {
    asm volatile("s_waitcnt vmcnt(0)" ::: "memory");
    __builtin_amdgcn_sched_barrier(0);
}
__device__ __forceinline__ void vmw2() {
    asm volatile("s_waitcnt vmcnt(2)" ::: "memory");
    __builtin_amdgcn_sched_barrier(0);
}
__device__ __forceinline__ void vmw4() {
    asm volatile("s_waitcnt vmcnt(4)" ::: "memory");
    __builtin_amdgcn_sched_barrier(0);
}

// ---- fused prep: eeg/pic f32->bf16 (blocks 0..4095) + 4 weight transposes
// (blocks 4096..5119). One dispatch saves a launch gap.
__global__ __launch_bounds__(256) void prep_all(
    const float* __restrict__ eeg, const float* __restrict__ pic,
    const float* __restrict__ W0, const float* __restrict__ W1,
    const float* __restrict__ W2, const float* __restrict__ W3,
    u16* __restrict__ Ae, u16* __restrict__ Ap,
    u16* __restrict__ T0, u16* __restrict__ T1,
    u16* __restrict__ T2, u16* __restrict__ T3)
{
    const int bx = (int)blockIdx.x;
    const int t = threadIdx.x;

    if (bx < 4096) {                    // converts
        const float* in = (bx >= 2048) ? pic : eeg;
        u16* out = (bx >= 2048) ? Ap : Ae;
        size_t i = ((size_t)(bx & 2047) * 256 + t) * 8;
        float4 x = *(const float4*)(in + i);
        float4 y = *(const float4*)(in + i + 4);
        u16x8 o;
        o[0]=f2bf(x.x); o[1]=f2bf(x.y); o[2]=f2bf(x.z); o[3]=f2bf(x.w);
        o[4]=f2bf(y.x); o[5]=f2bf(y.y); o[6]=f2bf(y.z); o[7]=f2bf(y.w);
        *(u16x8*)(out + i) = o;
        return;
    }

    // transpose W[K][N] f32 -> Wt[N][K] bf16, 64x64 tiles via LDS
    const int idx = bx - 4096;          // 0..1023
    const int z = idx >> 8;
    const int rem = idx & 255;
    const int k0 = (rem & 15) * 64, n0 = (rem >> 4) * 64;
    const float* W = (z==0)?W0:(z==1)?W1:(z==2)?W2:W3;
    u16* Wt = (z==0)?T0:(z==1)?T1:(z==2)?T2:T3;

    __shared__ float Ls[64][65];
    #pragma unroll
    for (int i = 0; i < 4; ++i) {
        int r = (t >> 4) + i * 16, c = (t & 15) * 4;
        float4 v = *(const float4*)&W[(size_t)(k0 + r) * DD + n0 + c];
        Ls[r][c] = v.x; Ls[r][c+1] = v.y; Ls[r][c+2] = v.z; Ls[r][c+3] = v.w;
    }
    __syncthreads();
    #pragma unroll
    for (int i = 0; i < 2; ++i) {
        int n = (t >> 3) + i * 32, kc = (t & 7) * 8;
        u16x8 o;
        #pragma unroll
        for (int j = 0; j < 8; ++j) o[j] = f2bf(Ls[kc + j][n]);
        *(u16x8*)&Wt[(size_t)(n0 + n) * DD + k0 + kc] = o;
    }
}

// ============================================================================
// 256x256 8-phase GEMM (T2 swizzle + T3/T4 counted vmcnt + T5 setprio)
// ============================================================================
template<int TRANS>
__device__ __forceinline__ void do_phase(
    const u16* Lcur, int wm, int wn, int g, int lr, int mh, int kh, f32x4* acc)
{
    const char* base = (const char*)Lcur;
    bf16x8 af[4], bfr[4];
    #pragma unroll
    for (int i = 0; i < 4; ++i) {
        int row = wm * 128 + mh * 64 + i * 16 + lr;
        af[i] = *(const bf16x8*)(base + row * 128 + ((kh * 4 + g) ^ (row & 7)) * 16);
    }
    #pragma unroll
    for (int i = 0; i < 4; ++i) {
        int row = wn * 64 + i * 16 + lr;
        bfr[i] = *(const bf16x8*)(base + 32768 + row * 128 + ((kh * 4 + g) ^ (row & 7)) * 16);
    }
    __builtin_amdgcn_s_setprio(1);
    #pragma unroll
    for (int i = 0; i < 4; ++i)
        #pragma unroll
        for (int j = 0; j < 4; ++j) {
            int mi = mh * 4 + i;
            if (TRANS)
                acc[j * 8 + mi] = __builtin_amdgcn_mfma_f32_16x16x32_bf16(
                    bfr[j], af[i], acc[j * 8 + mi], 0, 0, 0);
            else
                acc[mi * 4 + j] = __builtin_amdgcn_mfma_f32_16x16x32_bf16(
                    af[i], bfr[j], acc[mi * 4 + j], 0, 0, 0);
        }
    __builtin_amdgcn_s_setprio(0);
}

template<int TRANS>
__device__ __forceinline__ void gemm256_8ph(
    const u16* __restrict__ A, const u16* __restrict__ Bt,
    int bm, int bn, u16* Ls, f32x4* acc)
{
    const int tid = threadIdx.x;
    const int w = tid >> 6, l = tid & 63, g = l >> 4, lr = l & 15;
    const int wm = w >> 2, wn = w & 3;

    const int srow = tid >> 3;                       // 0..63
    const int sgc = (tid & 7) ^ (srow & 7);          // pre-swizzled source chunk
    const u16* Ag = A + (size_t)(bm + srow) * DD + sgc * 8;
    const u16* Bg = Bt + (size_t)(bn + srow) * DD + sgc * 8;

#define STA(buf, r, k0) gload16(Ag + (size_t)(r) * 64 * DD + (k0), (buf) + (r) * 4096 + w * 512)
#define STB(buf, r, k0) gload16(Bg + (size_t)(r) * 64 * DD + (k0), (buf) + 16384 + (r) * 4096 + w * 512)

    STB(Ls, 0, 0); STB(Ls, 1, 0);
    STB(Ls, 2, 0); STB(Ls, 3, 0);
    STA(Ls, 0, 0); STA(Ls, 2, 0);
    STA(Ls, 1, 0); STA(Ls, 3, 0);

    #pragma unroll 2
    for (int t = 0; t < 16; ++t) {
        const int cur = t & 1;
        const u16* cb = Ls + cur * 32768;
        u16* nb = Ls + (cur ^ 1) * 32768;
        const int nk = (t + 1) * 64;
        const bool last = (t == 15);

        vmw2();
        __builtin_amdgcn_s_barrier();
        if (!last) { STB(nb, 0, nk); STB(nb, 1, nk); }
        do_phase<TRANS>(cb, wm, wn, g, lr, 0, 0, acc);

        __builtin_amdgcn_s_barrier();
        if (!last) { STB(nb, 2, nk); STB(nb, 3, nk); }
        do_phase<TRANS>(cb, wm, wn, g, lr, 0, 1, acc);

        if (last) vmw0(); else vmw4();
        __builtin_amdgcn_s_barrier();
        if (!last) { STA(nb, 0, nk); STA(nb, 2, nk); }
        do_phase<TRANS>(cb, wm, wn, g, lr, 1, 0, acc);

        __builtin_amdgcn_s_barrier();
        if (!last) { STA(nb, 1, nk); STA(nb, 3, nk); }
        do_phase<TRANS>(cb, wm, wn, g, lr, 1, 1, acc);
    }
#undef STA
#undef STB
}

// fused QKV, 256^2 tiles: grid 192 = 8 XCD x (3 sel x 8 tiles)
__global__ __launch_bounds__(512, 2) void gemm_qkv(
    const u16* __restrict__ Ae, const u16* __restrict__ Ap,
    const u16* __restrict__ Bk, const u16* __restrict__ Bq, const u16* __restrict__ Bv,
    const float* __restrict__ bk, const float* __restrict__ bq, const float* __restrict__ bv,
    u16* __restrict__ Kb, u16* __restrict__ Qb, u16* __restrict__ VtG)
{
    const int i = (int)blockIdx.x;
    const int x = i & 7, j = i >> 3;
    const int sel = j >> 3, inner = j & 7;
    const int bm = (x * 2 + (inner & 1)) * 256;
    const int bn = (inner >> 1) * 256;

    const u16* A  = sel ? Ap : Ae;
    const u16* Bt = (sel == 0) ? Bk : (sel == 1) ? Bq : Bv;
    const float* bias = (sel == 0) ? bk : (sel == 1) ? bq : bv;
    const float alpha = (sel == 1) ? 0.180336880111120f : 1.0f;  // 0.125*log2e

    __shared__ __align__(16) u16 Ls[2 * 32768];

    f32x4 acc[32];
    #pragma unroll
    for (int k = 0; k < 32; ++k) { f32x4 z = {0,0,0,0}; acc[k] = z; }

    const int tid = threadIdx.x;
    const int w = tid >> 6, l = tid & 63, g = l >> 4, lr = l & 15;
    const int wm = w >> 2, wn = w & 3;

    if (sel == 2) {
        gemm256_8ph<1>(A, Bt, bm, bn, Ls, acc);
        #pragma unroll
        for (int ni = 0; ni < 4; ++ni)
            #pragma unroll
            for (int r = 0; r < 4; ++r) {
                int n = bn + wn * 64 + ni * 16 + g * 4 + r;
                float bb = bias[n];
                #pragma unroll
                for (int mi = 0; mi < 8; ++mi) {
                    int m = bm + wm * 128 + mi * 16 + lr;
                    VtG[(size_t)n * MM + m] = f2bf(acc[ni * 8 + mi][r] + bb);
                }
            }
    } else {
        gemm256_8ph<0>(A, Bt, bm, bn, Ls, acc);
        u16* C = sel ? Qb : Kb;
        float b4[4];
        #pragma unroll
        for (int ni = 0; ni < 4; ++ni) b4[ni] = bias[bn + wn * 64 + ni * 16 + lr];
        #pragma unroll
        for (int mi = 0; mi < 8; ++mi)
            #pragma unroll
            for (int ni = 0; ni < 4; ++ni)
                #pragma unroll
                for (int r = 0; r < 4; ++r) {
                    int row = bm + wm * 128 + mi * 16 + g * 4 + r;
                    int col = bn + wn * 64 + ni * 16 + lr;
                    C[(size_t)row * DD + col] = f2bf(alpha * (acc[mi * 4 + ni][r] + b4[ni]));
                }
    }
}

// ---- 128x128 2-phase mainloop (kept for gemm_plain) ------------------------
template<int TRANS>
__device__ __forceinline__ void gemm128_loop(
    const u16* __restrict__ A, const u16* __restrict__ Bt,
    int bm, int bn, u16* As, u16* Bs, f32x4 (&acc)[4][4])
{
    const int tid = threadIdx.x;
    const int w = tid >> 6, l = tid & 63, g = l >> 4, lr = l & 15;
    const int wm = w >> 1, wn = w & 1;

    const int srow = tid >> 3, ss = tid & 7;
    const int sgc = ss ^ (srow & 7);
    const u16* Ag = A + (size_t)(bm + srow) * DD + sgc * 8;
    const u16* Bg = Bt + (size_t)(bn + srow) * DD + sgc * 8;

    for (int k0 = 0; k0 < DD; k0 += 64) {
        #pragma unroll
        for (int rr = 0; rr < 4; ++rr)
            gload16(Ag + (size_t)rr * 32 * DD + k0, As + (rr * 256 + w * 64) * 8);
        #pragma unroll
        for (int rr = 0; rr < 4; ++rr)
            gload16(Bg + (size_t)rr * 32 * DD + k0, Bs + (rr * 256 + w * 64) * 8);
        __syncthreads();

        #pragma unroll
        for (int kh = 0; kh < 2; ++kh) {
            bf16x8 af[4], bfr[4];
            #pragma unroll
            for (int mi = 0; mi < 4; ++mi) {
                int row = wm * 64 + mi * 16 + lr;
                af[mi] = *(const bf16x8*)((const char*)As + row * 128 +
                                          ((kh * 4 + g) ^ (row & 7)) * 16);
            }
            #pragma unroll
            for (int ni = 0; ni < 4; ++ni) {
                int row = wn * 64 + ni * 16 + lr;
                bfr[ni] = *(const bf16x8*)((const char*)Bs + row * 128 +
                                           ((kh * 4 + g) ^ (row & 7)) * 16);
            }
            #pragma unroll
            for (int mi = 0; mi < 4; ++mi)
                #pragma unroll
                for (int ni = 0; ni < 4; ++ni) {
                    if (TRANS)
                        acc[ni][mi] = __builtin_amdgcn_mfma_f32_16x16x32_bf16(
                            bfr[ni], af[mi], acc[ni][mi], 0, 0, 0);
                    else
                        acc[mi][ni] = __builtin_amdgcn_mfma_f32_16x16x32_bf16(
                            af[mi], bfr[ni], acc[mi][ni], 0, 0, 0);
                }
        }
        __syncthreads();
    }
}

__global__ __launch_bounds__(256) void gemm_plain(
    const u16* __restrict__ A, const u16* __restrict__ Bt,
    const float* __restrict__ bias, u16* __restrict__ C)
{
    const int i = (int)blockIdx.x;
    const int x = i & 7, j = i >> 3;
    const int bn = (j >> 2) * 128;
    const int bm = (x * 4 + (j & 3)) * 128;

    __shared__ __align__(16) u16 As[128 * 64];
    __shared__ __align__(16) u16 Bs[128 * 64];

    f32x4 acc[4][4];
    #pragma unroll
    for (int a = 0; a < 4; ++a)
        #pragma unroll
        for (int b = 0; b < 4; ++b) { f32x4 z = {0,0,0,0}; acc[a][b] = z; }

    gemm128_loop<0>(A, Bt, bm, bn, As, Bs, acc);

    const int tid = threadIdx.x;
    const int w = tid >> 6, l = tid & 63, g = l >> 4, lr = l & 15;
    const int wm = w >> 1, wn = w & 1;
    float b4[4];
    #pragma unroll
    for (int ni = 0; ni < 4; ++ni) b4[ni] = bias[bn + wn * 64 + ni * 16 + lr];
    #pragma unroll
    for (int mi = 0; mi < 4; ++mi)
        #pragma unroll
        for (int ni = 0; ni < 4; ++ni)
            #pragma unroll
            for (int r = 0; r < 4; ++r) {
                int row = bm + wm * 64 + mi * 16 + g * 4 + r;
                int col = bn + wn * 64 + ni * 16 + lr;
                C[(size_t)row * DD + col] = f2bf(acc[mi][ni][r] + b4[ni]);
            }
}

// ============================================================================
// MFMA flash attention — R11 structure (best measured: 39.6 us) with
// FIXED-MAX softmax: p = exp2(st - 32). Exactly softmax (power-of-2 shift
// cancels in the division); st ~ N(0,~2) so overflow needs st>160 — absurd.
// Removes per-iter tmax reduce (16 fmax + 2 bpermute), __all ballot, and
// the rescale path entirely. T15 two-tile pipeline, tri-buffered K/V,
// counted vmcnt + one raw barrier per iter, swizzled P LDS, deferred l.
// ============================================================================
#define SM_M 32.0f

__device__ __forceinline__ void qk_tile(
    f32x4 (&st)[4], const u16* kbuf, const bf16x8 (&qf)[2], int g, int lr)
{
    __builtin_amdgcn_s_setprio(1);
    #pragma unroll
    for (int kt = 0; kt < 4; ++kt) {
        int row = kt * 16 + lr;
        const char* rb = (const char*)kbuf + row * 128;
        bf16x8 k0 = *(const bf16x8*)(rb + ((0 + g) ^ (row & 7)) * 16);
        bf16x8 k1 = *(const bf16x8*)(rb + ((4 + g) ^ (row & 7)) * 16);
        f32x4 z = {0,0,0,0};
        z = __builtin_amdgcn_mfma_f32_16x16x32_bf16(k0, qf[0], z, 0, 0, 0);
        z = __builtin_amdgcn_mfma_f32_16x16x32_bf16(k1, qf[1], z, 0, 0, 0);
        st[kt] = z;
    }
    __builtin_amdgcn_s_setprio(0);
}

__global__ __launch_bounds__(512) void attn_mfma(
    const u16* __restrict__ Q, const u16* __restrict__ K,
    const u16* __restrict__ Vt, u16* __restrict__ O)
{
    const int tid = threadIdx.x;
    const int w = tid >> 6, l = tid & 63, g = l >> 4, lr = l & 15;
    int bid = (int)blockIdx.x;
    bid = (bid & 7) * 64 + (bid >> 3);           // XCD-bijective (512 % 8 == 0)
    const int qb = bid & 7, h = (bid >> 3) & 15, b = bid >> 7;
    const size_t qrow0 = (size_t)b * SS + qb * 128;
    const size_t kv0 = (size_t)b * SS;
    const int hc = h * HD;

    __shared__ __align__(16) u16 Ks[3][4096];    // 24KB triple buf, swizzled rows
    __shared__ __align__(16) u16 Vs[3][4096];    // 24KB (V^T: d-rows, keys inner)
    __shared__ __align__(16) u16 Ps[8][1024];    // 16KB per-wave P, 128B swizzled rows

    const int srow = tid >> 3, ss = tid & 7;
    const int sgc = ss ^ (srow & 7);
    const u16* kg = K + (kv0 + srow) * DD + hc + sgc * 8;
    const u16* vg = Vt + (size_t)(hc + srow) * MM + kv0 + sgc * 8;

#define STG(t) do { \
    gload16(kg + (size_t)(t) * 64 * DD, &Ks[(t) % 3][w * 512]); \
    gload16(vg + (size_t)(t) * 64,      &Vs[(t) % 3][w * 512]); } while (0)

    bf16x8 qf[2];
    {
        const u16* qp = Q + (qrow0 + w * 16 + lr) * DD + hc + g * 8;
        qf[0] = *(const bf16x8*)(qp);
        qf[1] = *(const bf16x8*)(qp + 32);
    }

    f32x4 acc[4];
    #pragma unroll
    for (int dt = 0; dt < 4; ++dt) { f32x4 z = {0,0,0,0}; acc[dt] = z; }
    float l_run = 0.f;                           // PER-LANE partial; reduce at end

    // prologue: stage tiles 0,1; wait tile 0; QK(0)
    STG(0); STG(1);
    vmw2();
    __builtin_amdgcn_s_barrier();

    f32x4 st[2][4];
    qk_tile(st[0], &Ks[0][0], qf, g, lr);

    #pragma unroll
    for (int t = 0; t < 16; ++t) {
        const int cur = t & 1;

        if (t < 15) {
            // wait stage(t+1) (issued a full iter ago), sync, then QK(t+1)
            vmw0();
            __builtin_amdgcn_s_barrier();
            qk_tile(st[cur ^ 1], &Ks[(t + 1) % 3][0], qf, g, lr);
            if (t + 2 < 16) STG(t + 2);   // into buf[(t+2)%3] = dead tile t-1
        }

        // ---- fixed-max softmax(t): p = exp2(st - 32); no max tracking ----
        float p[16];
        float ps = 0.f;
        #pragma unroll
        for (int kt = 0; kt < 4; ++kt)
            #pragma unroll
            for (int r = 0; r < 4; ++r) {
                float v = exp2f(st[cur][kt][r] - SM_M);
                p[kt * 4 + r] = v;
                ps += v;
            }
        l_run += ps;                              // deferred: no per-iter reduce

        // P -> per-wave LDS, 128B rows, XOR chunk swizzle
        #pragma unroll
        for (int kt = 0; kt < 4; ++kt) {
            u16x4 h4;
            #pragma unroll
            for (int r = 0; r < 4; ++r) h4[r] = f2bf(p[kt * 4 + r]);
            int ch = (2 * kt + (g >> 1)) ^ (lr & 7);
            *(u16x4*)((char*)&Ps[w][0] + lr * 128 + ch * 16 + (g & 1) * 8) = h4;
        }

        // ---- PV(t): acc += P(t) @ V(t) ----
        const char* vbase = (const char*)&Vs[t % 3][0];
        __builtin_amdgcn_s_setprio(1);
        #pragma unroll
        for (int kh = 0; kh < 2; ++kh) {
            bf16x8 pf = *(const bf16x8*)((const char*)&Ps[w][0] + lr * 128 +
                                         (((4 * kh + g) ^ (lr & 7))) * 16);
            #pragma unroll
            for (int dt = 0; dt < 4; ++dt) {
                int row = dt * 16 + lr;
                bf16x8 vf = *(const bf16x8*)(vbase + row * 128 +
                                             ((kh * 4 + g) ^ (row & 7)) * 16);
                acc[dt] = __builtin_amdgcn_mfma_f32_16x16x32_bf16(pf, vf, acc[dt], 0, 0, 0);
            }
        }
        __builtin_amdgcn_s_setprio(0);
    }
#undef STG

    // epilogue: finish deferred l reduce, divide, store
    float l_tot = l_run;
    l_tot += __shfl_xor(l_tot, 16);
    l_tot += __shfl_xor(l_tot, 32);
    float invl[4];
    #pragma unroll
    for (int r = 0; r < 4; ++r) invl[r] = 1.f / __shfl(l_tot, g * 4 + r);
    #pragma unroll
    for (int dt = 0; dt < 4; ++dt)
        #pragma unroll
        for (int r = 0; r < 4; ++r) {
            size_t row = qrow0 + w * 16 + g * 4 + r;
            O[row * DD + hc + dt * 16 + lr] = f2bf(acc[dt][r] * invl[r]);
        }
}

// ---- residual + LayerNorm --------------------------------------------------
__global__ __launch_bounds__(256) void ln_kernel(
    const u16* __restrict__ Hs, const float* __restrict__ P,
    const float* __restrict__ w, const float* __restrict__ bshift,
    float* __restrict__ out)
{
    const int row = blockIdx.x;
    const int tid = threadIdx.x;
    const size_t off = (size_t)row * DD;
    const int c0 = tid * 4;

    u16x4 h4 = *(const u16x4*)&Hs[off + c0];
    float4 p4 = *(const float4*)&P[off + c0];
    float x[4];
    x[0] = bf2f(h4[0]) + p4.x; x[1] = bf2f(h4[1]) + p4.y;
    x[2] = bf2f(h4[2]) + p4.z; x[3] = bf2f(h4[3]) + p4.w;

    float s = x[0] + x[1] + x[2] + x[3];
    #pragma unroll
    for (int o = 32; o >= 1; o >>= 1) s += __shfl_xor(s, o, 64);

    __shared__ float r1[4], r2[4];
    const int wid = tid >> 6;
    if ((tid & 63) == 0) r1[wid] = s;
    __syncthreads();
    const float mean = (r1[0] + r1[1] + r1[2] + r1[3]) * (1.f / (float)DD);

    float d2 = 0.f;
    #pragma unroll
    for (int i = 0; i < 4; ++i) { float d = x[i] - mean; d2 += d * d; }
    #pragma unroll
    for (int o = 32; o >= 1; o >>= 1) d2 += __shfl_xor(d2, o, 64);
    if ((tid & 63) == 0) r2[wid] = d2;
    __syncthreads();
    const float var = (r2[0] + r2[1] + r2[2] + r2[3]) * (1.f / (float)DD);
    const float inv = rsqrtf(var + LN_EPS);

    float4 o4;
    o4.x = w[c0 + 0] * ((x[0] - mean) * inv) + bshift[c0 + 0];
    o4.y = w[c0 + 1] * ((x[1] - mean) * inv) + bshift[c0 + 1];
    o4.z = w[c0 + 2] * ((x[2] - mean) * inv) + bshift[c0 + 2];
    o4.w = w[c0 + 3] * ((x[3] - mean) * inv) + bshift[c0 + 3];
    *(float4*)&out[off + c0] = o4;
}

// ---------------------------------------------------------------------------
extern "C" void kernel_launch(void* const* d_in, const int* in_sizes, int n_in,
                              void* d_out, int out_size, void* d_ws, size_t ws_size,
                              hipStream_t stream)
{
    const float* eeg = (const float*)d_in[0];
    const float* pic = (const float*)d_in[1];
    const float* Wk  = (const float*)d_in[2];
    const float* bk  = (const float*)d_in[3];
    const float* Wq  = (const float*)d_in[4];
    const float* bq  = (const float*)d_in[5];
    const float* Wv  = (const float*)d_in[6];
    const float* bv  = (const float*)d_in[7];
    const float* Wd  = (const float*)d_in[8];
    const float* bd  = (const float*)d_in[9];
    const float* lnw = (const float*)d_in[10];
    const float* lnb = (const float*)d_in[11];
    float* out = (float*)d_out;

    u16* ws = (u16*)d_ws;
    const size_t M4 = (size_t)1 << 22;   // 4M elems
    u16* Ae  = ws;                       // eeg bf16 [M][D]
    u16* Ap  = ws + M4;                  // pic bf16
    u16* WtK = ws + 2 * M4;              // W^T bf16 [N][K]
    u16* WtQ = WtK + (1u << 20);
    u16* WtV = WtQ + (1u << 20);
    u16* WtD = WtV + (1u << 20);
    u16* Kb  = ws + 3 * M4;              // K  [M][D]
    u16* Qb  = ws + 4 * M4;              // Q (pre-scaled) [M][D]
    u16* VtG = ws + 5 * M4;              // V^T [D][M]
    u16* Cb  = ws + 6 * M4;              // ctx [M][D]
    u16* Hb  = ws + 7 * M4;              // H   [M][D]

    prep_all<<<5120, 256, 0, stream>>>(eeg, pic, Wk, Wq, Wv, Wd,
                                       Ae, Ap, WtK, WtQ, WtV, WtD);

    gemm_qkv<<<192, 512, 0, stream>>>(Ae, Ap, WtK, WtQ, WtV,
                                      bk, bq, bv, Kb, Qb, VtG);

    attn_mfma<<<BB * HH * (SS / 128), 512, 0, stream>>>(Qb, Kb, VtG, Cb);

    gemm_plain<<<256, 256, 0, stream>>>(Cb, WtD, bd, Hb);

    ln_kernel<<<MM, 256, 0, stream>>>(Hb, pic, lnw, lnb, out);
}

// Round 13
// 108.763 us; speedup vs baseline: 1.2715x; 1.2715x over previous
//
#include <hip/hip_runtime.h>
#include <hip/hip_bf16.h>

// B=4, S=1024, D=1024, H=16, HD=64
#define BB 4
#define SS 1024
#define DD 1024
#define HH 16
#define HD 64
#define MM (BB * SS)
#define LN_EPS 1e-12f

typedef unsigned short u16;
typedef unsigned int u32;
typedef __attribute__((ext_vector_type(8))) short bf16x8;
typedef __attribute__((ext_vector_type(4))) float f32x4;
typedef __attribute__((ext_vector_type(4))) unsigned short u16x4;
typedef __attribute__((ext_vector_type(8))) unsigned short u16x8;

// ---- helpers ---------------------------------------------------------------
__device__ __forceinline__ u16 f2bf(float f) {          // compiler-native RNE cast
    __hip_bfloat16 h = __float2bfloat16(f);
    u16 r; __builtin_memcpy(&r, &h, 2); return r;
}
__device__ __forceinline__ float bf2f(u16 u) {
    unsigned v = ((unsigned)u) << 16;
    float f; __builtin_memcpy(&f, &v, 4); return f;
}

typedef const __attribute__((address_space(1))) unsigned int* gas1_t;
typedef __attribute__((address_space(3))) unsigned int* las3_t;
__device__ __forceinline__ void gload16(const void* g, void* s) {
    __builtin_amdgcn_global_load_lds((gas1_t)g, (las3_t)s, 16, 0, 0);
}

// counted vmem waits (raw; never full-drain in steady state)
__device__ __forceinline__ void vmw0() {
    asm volatile("s_waitcnt vmcnt(0)" ::: "memory");
    __builtin_amdgcn_sched_barrier(0);
}
__device__ __forceinline__ void vmw2() {
    asm volatile("s_waitcnt vmcnt(2)" ::: "memory");
    __builtin_amdgcn_sched_barrier(0);
}
__device__ __forceinline__ void vmw4() {
    asm volatile("s_waitcnt vmcnt(4)" ::: "memory");
    __builtin_amdgcn_sched_barrier(0);
}

// ---- fused prep: eeg/pic f32->bf16 (blocks 0..4095) + 4 weight transposes
// (blocks 4096..5119). One dispatch saves a launch gap.
__global__ __launch_bounds__(256) void prep_all(
    const float* __restrict__ eeg, const float* __restrict__ pic,
    const float* __restrict__ W0, const float* __restrict__ W1,
    const float* __restrict__ W2, const float* __restrict__ W3,
    u16* __restrict__ Ae, u16* __restrict__ Ap,
    u16* __restrict__ T0, u16* __restrict__ T1,
    u16* __restrict__ T2, u16* __restrict__ T3)
{
    const int bx = (int)blockIdx.x;
    const int t = threadIdx.x;

    if (bx < 4096) {                    // converts
        const float* in = (bx >= 2048) ? pic : eeg;
        u16* out = (bx >= 2048) ? Ap : Ae;
        size_t i = ((size_t)(bx & 2047) * 256 + t) * 8;
        float4 x = *(const float4*)(in + i);
        float4 y = *(const float4*)(in + i + 4);
        u16x8 o;
        o[0]=f2bf(x.x); o[1]=f2bf(x.y); o[2]=f2bf(x.z); o[3]=f2bf(x.w);
        o[4]=f2bf(y.x); o[5]=f2bf(y.y); o[6]=f2bf(y.z); o[7]=f2bf(y.w);
        *(u16x8*)(out + i) = o;
        return;
    }

    // transpose W[K][N] f32 -> Wt[N][K] bf16, 64x64 tiles via LDS
    const int idx = bx - 4096;          // 0..1023
    const int z = idx >> 8;
    const int rem = idx & 255;
    const int k0 = (rem & 15) * 64, n0 = (rem >> 4) * 64;
    const float* W = (z==0)?W0:(z==1)?W1:(z==2)?W2:W3;
    u16* Wt = (z==0)?T0:(z==1)?T1:(z==2)?T2:T3;

    __shared__ float Ls[64][65];
    #pragma unroll
    for (int i = 0; i < 4; ++i) {
        int r = (t >> 4) + i * 16, c = (t & 15) * 4;
        float4 v = *(const float4*)&W[(size_t)(k0 + r) * DD + n0 + c];
        Ls[r][c] = v.x; Ls[r][c+1] = v.y; Ls[r][c+2] = v.z; Ls[r][c+3] = v.w;
    }
    __syncthreads();
    #pragma unroll
    for (int i = 0; i < 2; ++i) {
        int n = (t >> 3) + i * 32, kc = (t & 7) * 8;
        u16x8 o;
        #pragma unroll
        for (int j = 0; j < 8; ++j) o[j] = f2bf(Ls[kc + j][n]);
        *(u16x8*)&Wt[(size_t)(n0 + n) * DD + k0 + kc] = o;
    }
}

// ============================================================================
// 256x256 8-phase GEMM (T2 swizzle + T3/T4 counted vmcnt + T5 setprio)
// ============================================================================
template<int TRANS>
__device__ __forceinline__ void do_phase(
    const u16* Lcur, int wm, int wn, int g, int lr, int mh, int kh, f32x4* acc)
{
    const char* base = (const char*)Lcur;
    bf16x8 af[4], bfr[4];
    #pragma unroll
    for (int i = 0; i < 4; ++i) {
        int row = wm * 128 + mh * 64 + i * 16 + lr;
        af[i] = *(const bf16x8*)(base + row * 128 + ((kh * 4 + g) ^ (row & 7)) * 16);
    }
    #pragma unroll
    for (int i = 0; i < 4; ++i) {
        int row = wn * 64 + i * 16 + lr;
        bfr[i] = *(const bf16x8*)(base + 32768 + row * 128 + ((kh * 4 + g) ^ (row & 7)) * 16);
    }
    __builtin_amdgcn_s_setprio(1);
    #pragma unroll
    for (int i = 0; i < 4; ++i)
        #pragma unroll
        for (int j = 0; j < 4; ++j) {
            int mi = mh * 4 + i;
            if (TRANS)
                acc[j * 8 + mi] = __builtin_amdgcn_mfma_f32_16x16x32_bf16(
                    bfr[j], af[i], acc[j * 8 + mi], 0, 0, 0);
            else
                acc[mi * 4 + j] = __builtin_amdgcn_mfma_f32_16x16x32_bf16(
                    af[i], bfr[j], acc[mi * 4 + j], 0, 0, 0);
        }
    __builtin_amdgcn_s_setprio(0);
}

template<int TRANS>
__device__ __forceinline__ void gemm256_8ph(
    const u16* __restrict__ A, const u16* __restrict__ Bt,
    int bm, int bn, u16* Ls, f32x4* acc)
{
    const int tid = threadIdx.x;
    const int w = tid >> 6, l = tid & 63, g = l >> 4, lr = l & 15;
    const int wm = w >> 2, wn = w & 3;

    const int srow = tid >> 3;                       // 0..63
    const int sgc = (tid & 7) ^ (srow & 7);          // pre-swizzled source chunk
    const u16* Ag = A + (size_t)(bm + srow) * DD + sgc * 8;
    const u16* Bg = Bt + (size_t)(bn + srow) * DD + sgc * 8;

#define STA(buf, r, k0) gload16(Ag + (size_t)(r) * 64 * DD + (k0), (buf) + (r) * 4096 + w * 512)
#define STB(buf, r, k0) gload16(Bg + (size_t)(r) * 64 * DD + (k0), (buf) + 16384 + (r) * 4096 + w * 512)

    STB(Ls, 0, 0); STB(Ls, 1, 0);
    STB(Ls, 2, 0); STB(Ls, 3, 0);
    STA(Ls, 0, 0); STA(Ls, 2, 0);
    STA(Ls, 1, 0); STA(Ls, 3, 0);

    #pragma unroll 2
    for (int t = 0; t < 16; ++t) {
        const int cur = t & 1;
        const u16* cb = Ls + cur * 32768;
        u16* nb = Ls + (cur ^ 1) * 32768;
        const int nk = (t + 1) * 64;
        const bool last = (t == 15);

        vmw2();
        __builtin_amdgcn_s_barrier();
        if (!last) { STB(nb, 0, nk); STB(nb, 1, nk); }
        do_phase<TRANS>(cb, wm, wn, g, lr, 0, 0, acc);

        __builtin_amdgcn_s_barrier();
        if (!last) { STB(nb, 2, nk); STB(nb, 3, nk); }
        do_phase<TRANS>(cb, wm, wn, g, lr, 0, 1, acc);

        if (last) vmw0(); else vmw4();
        __builtin_amdgcn_s_barrier();
        if (!last) { STA(nb, 0, nk); STA(nb, 2, nk); }
        do_phase<TRANS>(cb, wm, wn, g, lr, 1, 0, acc);

        __builtin_amdgcn_s_barrier();
        if (!last) { STA(nb, 1, nk); STA(nb, 3, nk); }
        do_phase<TRANS>(cb, wm, wn, g, lr, 1, 1, acc);
    }
#undef STA
#undef STB
}

// fused QKV, 256^2 tiles: grid 192 = 8 XCD x (3 sel x 8 tiles)
__global__ __launch_bounds__(512, 2) void gemm_qkv(
    const u16* __restrict__ Ae, const u16* __restrict__ Ap,
    const u16* __restrict__ Bk, const u16* __restrict__ Bq, const u16* __restrict__ Bv,
    const float* __restrict__ bk, const float* __restrict__ bq, const float* __restrict__ bv,
    u16* __restrict__ Kb, u16* __restrict__ Qb, u16* __restrict__ VtG)
{
    const int i = (int)blockIdx.x;
    const int x = i & 7, j = i >> 3;
    const int sel = j >> 3, inner = j & 7;
    const int bm = (x * 2 + (inner & 1)) * 256;
    const int bn = (inner >> 1) * 256;

    const u16* A  = sel ? Ap : Ae;
    const u16* Bt = (sel == 0) ? Bk : (sel == 1) ? Bq : Bv;
    const float* bias = (sel == 0) ? bk : (sel == 1) ? bq : bv;
    const float alpha = (sel == 1) ? 0.180336880111120f : 1.0f;  // 0.125*log2e

    __shared__ __align__(16) u16 Ls[2 * 32768];

    f32x4 acc[32];
    #pragma unroll
    for (int k = 0; k < 32; ++k) { f32x4 z = {0,0,0,0}; acc[k] = z; }

    const int tid = threadIdx.x;
    const int w = tid >> 6, l = tid & 63, g = l >> 4, lr = l & 15;
    const int wm = w >> 2, wn = w & 3;

    if (sel == 2) {
        gemm256_8ph<1>(A, Bt, bm, bn, Ls, acc);
        #pragma unroll
        for (int ni = 0; ni < 4; ++ni)
            #pragma unroll
            for (int r = 0; r < 4; ++r) {
                int n = bn + wn * 64 + ni * 16 + g * 4 + r;
                float bb = bias[n];
                #pragma unroll
                for (int mi = 0; mi < 8; ++mi) {
                    int m = bm + wm * 128 + mi * 16 + lr;
                    VtG[(size_t)n * MM + m] = f2bf(acc[ni * 8 + mi][r] + bb);
                }
            }
    } else {
        gemm256_8ph<0>(A, Bt, bm, bn, Ls, acc);
        u16* C = sel ? Qb : Kb;
        float b4[4];
        #pragma unroll
        for (int ni = 0; ni < 4; ++ni) b4[ni] = bias[bn + wn * 64 + ni * 16 + lr];
        #pragma unroll
        for (int mi = 0; mi < 8; ++mi)
            #pragma unroll
            for (int ni = 0; ni < 4; ++ni)
                #pragma unroll
                for (int r = 0; r < 4; ++r) {
                    int row = bm + wm * 128 + mi * 16 + g * 4 + r;
                    int col = bn + wn * 64 + ni * 16 + lr;
                    C[(size_t)row * DD + col] = f2bf(alpha * (acc[mi * 4 + ni][r] + b4[ni]));
                }
    }
}

// ---- 128x128 2-phase mainloop (kept for gemm_plain) ------------------------
template<int TRANS>
__device__ __forceinline__ void gemm128_loop(
    const u16* __restrict__ A, const u16* __restrict__ Bt,
    int bm, int bn, u16* As, u16* Bs, f32x4 (&acc)[4][4])
{
    const int tid = threadIdx.x;
    const int w = tid >> 6, l = tid & 63, g = l >> 4, lr = l & 15;
    const int wm = w >> 1, wn = w & 1;

    const int srow = tid >> 3, ss = tid & 7;
    const int sgc = ss ^ (srow & 7);
    const u16* Ag = A + (size_t)(bm + srow) * DD + sgc * 8;
    const u16* Bg = Bt + (size_t)(bn + srow) * DD + sgc * 8;

    for (int k0 = 0; k0 < DD; k0 += 64) {
        #pragma unroll
        for (int rr = 0; rr < 4; ++rr)
            gload16(Ag + (size_t)rr * 32 * DD + k0, As + (rr * 256 + w * 64) * 8);
        #pragma unroll
        for (int rr = 0; rr < 4; ++rr)
            gload16(Bg + (size_t)rr * 32 * DD + k0, Bs + (rr * 256 + w * 64) * 8);
        __syncthreads();

        #pragma unroll
        for (int kh = 0; kh < 2; ++kh) {
            bf16x8 af[4], bfr[4];
            #pragma unroll
            for (int mi = 0; mi < 4; ++mi) {
                int row = wm * 64 + mi * 16 + lr;
                af[mi] = *(const bf16x8*)((const char*)As + row * 128 +
                                          ((kh * 4 + g) ^ (row & 7)) * 16);
            }
            #pragma unroll
            for (int ni = 0; ni < 4; ++ni) {
                int row = wn * 64 + ni * 16 + lr;
                bfr[ni] = *(const bf16x8*)((const char*)Bs + row * 128 +
                                           ((kh * 4 + g) ^ (row & 7)) * 16);
            }
            #pragma unroll
            for (int mi = 0; mi < 4; ++mi)
                #pragma unroll
                for (int ni = 0; ni < 4; ++ni) {
                    if (TRANS)
                        acc[ni][mi] = __builtin_amdgcn_mfma_f32_16x16x32_bf16(
                            bfr[ni], af[mi], acc[ni][mi], 0, 0, 0);
                    else
                        acc[mi][ni] = __builtin_amdgcn_mfma_f32_16x16x32_bf16(
                            af[mi], bfr[ni], acc[mi][ni], 0, 0, 0);
                }
        }
        __syncthreads();
    }
}

__global__ __launch_bounds__(256) void gemm_plain(
    const u16* __restrict__ A, const u16* __restrict__ Bt,
    const float* __restrict__ bias, u16* __restrict__ C)
{
    const int i = (int)blockIdx.x;
    const int x = i & 7, j = i >> 3;
    const int bn = (j >> 2) * 128;
    const int bm = (x * 4 + (j & 3)) * 128;

    __shared__ __align__(16) u16 As[128 * 64];
    __shared__ __align__(16) u16 Bs[128 * 64];

    f32x4 acc[4][4];
    #pragma unroll
    for (int a = 0; a < 4; ++a)
        #pragma unroll
        for (int b = 0; b < 4; ++b) { f32x4 z = {0,0,0,0}; acc[a][b] = z; }

    gemm128_loop<0>(A, Bt, bm, bn, As, Bs, acc);

    const int tid = threadIdx.x;
    const int w = tid >> 6, l = tid & 63, g = l >> 4, lr = l & 15;
    const int wm = w >> 1, wn = w & 1;
    float b4[4];
    #pragma unroll
    for (int ni = 0; ni < 4; ++ni) b4[ni] = bias[bn + wn * 64 + ni * 16 + lr];
    #pragma unroll
    for (int mi = 0; mi < 4; ++mi)
        #pragma unroll
        for (int ni = 0; ni < 4; ++ni)
            #pragma unroll
            for (int r = 0; r < 4; ++r) {
                int row = bm + wm * 64 + mi * 16 + g * 4 + r;
                int col = bn + wn * 64 + ni * 16 + lr;
                C[(size_t)row * DD + col] = f2bf(acc[mi][ni][r] + b4[ni]);
            }
}

// ============================================================================
// MFMA flash attention — R11 structure (best measured: 39.6 us total 109.0):
// T15 two-tile pipeline, triple-buffered K/V, counted vmcnt + one raw
// barrier per iter, swizzled P LDS, per-lane deferred l-reduce.
// NOTE (R12 lesson): do NOT remove the __all/rescale branch — branch-free
// fully-unrolled body lets the compiler pipeline across iterations,
// blowing VGPR 52 -> 128 + 61 MB scratch (attn 39.6 -> 70 us).
// ============================================================================
__device__ __forceinline__ void qk_tile(
    f32x4 (&st)[4], const u16* kbuf, const bf16x8 (&qf)[2], int g, int lr)
{
    __builtin_amdgcn_s_setprio(1);
    #pragma unroll
    for (int kt = 0; kt < 4; ++kt) {
        int row = kt * 16 + lr;
        const char* rb = (const char*)kbuf + row * 128;
        bf16x8 k0 = *(const bf16x8*)(rb + ((0 + g) ^ (row & 7)) * 16);
        bf16x8 k1 = *(const bf16x8*)(rb + ((4 + g) ^ (row & 7)) * 16);
        f32x4 z = {0,0,0,0};
        z = __builtin_amdgcn_mfma_f32_16x16x32_bf16(k0, qf[0], z, 0, 0, 0);
        z = __builtin_amdgcn_mfma_f32_16x16x32_bf16(k1, qf[1], z, 0, 0, 0);
        st[kt] = z;
    }
    __builtin_amdgcn_s_setprio(0);
}

__global__ __launch_bounds__(512) void attn_mfma(
    const u16* __restrict__ Q, const u16* __restrict__ K,
    const u16* __restrict__ Vt, u16* __restrict__ O)
{
    const int tid = threadIdx.x;
    const int w = tid >> 6, l = tid & 63, g = l >> 4, lr = l & 15;
    int bid = (int)blockIdx.x;
    bid = (bid & 7) * 64 + (bid >> 3);           // XCD-bijective (512 % 8 == 0)
    const int qb = bid & 7, h = (bid >> 3) & 15, b = bid >> 7;
    const size_t qrow0 = (size_t)b * SS + qb * 128;
    const size_t kv0 = (size_t)b * SS;
    const int hc = h * HD;

    __shared__ __align__(16) u16 Ks[3][4096];    // 24KB triple buf, swizzled rows
    __shared__ __align__(16) u16 Vs[3][4096];    // 24KB (V^T: d-rows, keys inner)
    __shared__ __align__(16) u16 Ps[8][1024];    // 16KB per-wave P, 128B swizzled rows

    const int srow = tid >> 3, ss = tid & 7;
    const int sgc = ss ^ (srow & 7);
    const u16* kg = K + (kv0 + srow) * DD + hc + sgc * 8;
    const u16* vg = Vt + (size_t)(hc + srow) * MM + kv0 + sgc * 8;

#define STG(t) do { \
    gload16(kg + (size_t)(t) * 64 * DD, &Ks[(t) % 3][w * 512]); \
    gload16(vg + (size_t)(t) * 64,      &Vs[(t) % 3][w * 512]); } while (0)

    bf16x8 qf[2];
    {
        const u16* qp = Q + (qrow0 + w * 16 + lr) * DD + hc + g * 8;
        qf[0] = *(const bf16x8*)(qp);
        qf[1] = *(const bf16x8*)(qp + 32);
    }

    f32x4 acc[4];
    #pragma unroll
    for (int dt = 0; dt < 4; ++dt) { f32x4 z = {0,0,0,0}; acc[dt] = z; }
    float m_run = -1e30f, l_run = 0.f;           // l_run: PER-LANE partial

    // prologue: stage tiles 0,1; wait tile 0; QK(0)
    STG(0); STG(1);
    vmw2();
    __builtin_amdgcn_s_barrier();

    f32x4 st[2][4];
    qk_tile(st[0], &Ks[0][0], qf, g, lr);

    #pragma unroll
    for (int t = 0; t < 16; ++t) {
        const int cur = t & 1;

        if (t < 15) {
            // wait stage(t+1) (issued a full iter ago), sync, then QK(t+1)
            vmw0();
            __builtin_amdgcn_s_barrier();
            qk_tile(st[cur ^ 1], &Ks[(t + 1) % 3][0], qf, g, lr);
            if (t + 2 < 16) STG(t + 2);   // into buf[(t+2)%3] = dead tile t-1
        }

        // ---- softmax(t) on st[cur] (VALU; overlaps QK(t+1) MFMA) ----
        float tmax = -1e30f;
        #pragma unroll
        for (int kt = 0; kt < 4; ++kt)
            #pragma unroll
            for (int r = 0; r < 4; ++r) tmax = fmaxf(tmax, st[cur][kt][r]);
        tmax = fmaxf(tmax, __shfl_xor(tmax, 16));
        tmax = fmaxf(tmax, __shfl_xor(tmax, 32));

        if (!__all(tmax <= m_run + 8.f)) {
            float m_new = fmaxf(m_run, tmax);
            float sc = exp2f(m_run - m_new);     // uniform across g-lanes of row lr
            m_run = m_new;
            l_run *= sc;
            float scq[4];
            #pragma unroll
            for (int r = 0; r < 4; ++r) scq[r] = __shfl(sc, g * 4 + r);
            #pragma unroll
            for (int dt = 0; dt < 4; ++dt)
                #pragma unroll
                for (int r = 0; r < 4; ++r) acc[dt][r] *= scq[r];
        }

        float p[16];
        float ps = 0.f;
        #pragma unroll
        for (int kt = 0; kt < 4; ++kt)
            #pragma unroll
            for (int r = 0; r < 4; ++r) {
                float v = exp2f(st[cur][kt][r] - m_run);
                p[kt * 4 + r] = v;
                ps += v;
            }
        l_run += ps;                              // deferred: no per-iter reduce

        // P -> per-wave LDS, 128B rows, XOR chunk swizzle
        #pragma unroll
        for (int kt = 0; kt < 4; ++kt) {
            u16x4 h4;
            #pragma unroll
            for (int r = 0; r < 4; ++r) h4[r] = f2bf(p[kt * 4 + r]);
            int ch = (2 * kt + (g >> 1)) ^ (lr & 7);
            *(u16x4*)((char*)&Ps[w][0] + lr * 128 + ch * 16 + (g & 1) * 8) = h4;
        }

        // ---- PV(t): acc += P(t) @ V(t) ----
        const char* vbase = (const char*)&Vs[t % 3][0];
        __builtin_amdgcn_s_setprio(1);
        #pragma unroll
        for (int kh = 0; kh < 2; ++kh) {
            bf16x8 pf = *(const bf16x8*)((const char*)&Ps[w][0] + lr * 128 +
                                         (((4 * kh + g) ^ (lr & 7))) * 16);
            #pragma unroll
            for (int dt = 0; dt < 4; ++dt) {
                int row = dt * 16 + lr;
                bf16x8 vf = *(const bf16x8*)(vbase + row * 128 +
                                             ((kh * 4 + g) ^ (row & 7)) * 16);
                acc[dt] = __builtin_amdgcn_mfma_f32_16x16x32_bf16(pf, vf, acc[dt], 0, 0, 0);
            }
        }
        __builtin_amdgcn_s_setprio(0);
    }
#undef STG

    // epilogue: finish deferred l reduce, divide, store
    float l_tot = l_run;
    l_tot += __shfl_xor(l_tot, 16);
    l_tot += __shfl_xor(l_tot, 32);
    float invl[4];
    #pragma unroll
    for (int r = 0; r < 4; ++r) invl[r] = 1.f / __shfl(l_tot, g * 4 + r);
    #pragma unroll
    for (int dt = 0; dt < 4; ++dt)
        #pragma unroll
        for (int r = 0; r < 4; ++r) {
            size_t row = qrow0 + w * 16 + g * 4 + r;
            O[row * DD + hc + dt * 16 + lr] = f2bf(acc[dt][r] * invl[r]);
        }
}

// ---- residual + LayerNorm --------------------------------------------------
__global__ __launch_bounds__(256) void ln_kernel(
    const u16* __restrict__ Hs, const float* __restrict__ P,
    const float* __restrict__ w, const float* __restrict__ bshift,
    float* __restrict__ out)
{
    const int row = blockIdx.x;
    const int tid = threadIdx.x;
    const size_t off = (size_t)row * DD;
    const int c0 = tid * 4;

    u16x4 h4 = *(const u16x4*)&Hs[off + c0];
    float4 p4 = *(const float4*)&P[off + c0];
    float x[4];
    x[0] = bf2f(h4[0]) + p4.x; x[1] = bf2f(h4[1]) + p4.y;
    x[2] = bf2f(h4[2]) + p4.z; x[3] = bf2f(h4[3]) + p4.w;

    float s = x[0] + x[1] + x[2] + x[3];
    #pragma unroll
    for (int o = 32; o >= 1; o >>= 1) s += __shfl_xor(s, o, 64);

    __shared__ float r1[4], r2[4];
    const int wid = tid >> 6;
    if ((tid & 63) == 0) r1[wid] = s;
    __syncthreads();
    const float mean = (r1[0] + r1[1] + r1[2] + r1[3]) * (1.f / (float)DD);

    float d2 = 0.f;
    #pragma unroll
    for (int i = 0; i < 4; ++i) { float d = x[i] - mean; d2 += d * d; }
    #pragma unroll
    for (int o = 32; o >= 1; o >>= 1) d2 += __shfl_xor(d2, o, 64);
    if ((tid & 63) == 0) r2[wid] = d2;
    __syncthreads();
    const float var = (r2[0] + r2[1] + r2[2] + r2[3]) * (1.f / (float)DD);
    const float inv = rsqrtf(var + LN_EPS);

    float4 o4;
    o4.x = w[c0 + 0] * ((x[0] - mean) * inv) + bshift[c0 + 0];
    o4.y = w[c0 + 1] * ((x[1] - mean) * inv) + bshift[c0 + 1];
    o4.z = w[c0 + 2] * ((x[2] - mean) * inv) + bshift[c0 + 2];
    o4.w = w[c0 + 3] * ((x[3] - mean) * inv) + bshift[c0 + 3];
    *(float4*)&out[off + c0] = o4;
}

// ---------------------------------------------------------------------------
extern "C" void kernel_launch(void* const* d_in, const int* in_sizes, int n_in,
                              void* d_out, int out_size, void* d_ws, size_t ws_size,
                              hipStream_t stream)
{
    const float* eeg = (const float*)d_in[0];
    const float* pic = (const float*)d_in[1];
    const float* Wk  = (const float*)d_in[2];
    const float* bk  = (const float*)d_in[3];
    const float* Wq  = (const float*)d_in[4];
    const float* bq  = (const float*)d_in[5];
    const float* Wv  = (const float*)d_in[6];
    const float* bv  = (const float*)d_in[7];
    const float* Wd  = (const float*)d_in[8];
    const float* bd  = (const float*)d_in[9];
    const float* lnw = (const float*)d_in[10];
    const float* lnb = (const float*)d_in[11];
    float* out = (float*)d_out;

    u16* ws = (u16*)d_ws;
    const size_t M4 = (size_t)1 << 22;   // 4M elems
    u16* Ae  = ws;                       // eeg bf16 [M][D]
    u16* Ap  = ws + M4;                  // pic bf16
    u16* WtK = ws + 2 * M4;              // W^T bf16 [N][K]
    u16* WtQ = WtK + (1u << 20);
    u16* WtV = WtQ + (1u << 20);
    u16* WtD = WtV + (1u << 20);
    u16* Kb  = ws + 3 * M4;              // K  [M][D]
    u16* Qb  = ws + 4 * M4;              // Q (pre-scaled) [M][D]
    u16* VtG = ws + 5 * M4;              // V^T [D][M]
    u16* Cb  = ws + 6 * M4;              // ctx [M][D]
    u16* Hb  = ws + 7 * M4;              // H   [M][D]

    prep_all<<<5120, 256, 0, stream>>>(eeg, pic, Wk, Wq, Wv, Wd,
                                       Ae, Ap, WtK, WtQ, WtV, WtD);

    gemm_qkv<<<192, 512, 0, stream>>>(Ae, Ap, WtK, WtQ, WtV,
                                      bk, bq, bv, Kb, Qb, VtG);

    attn_mfma<<<BB * HH * (SS / 128), 512, 0, stream>>>(Qb, Kb, VtG, Cb);

    gemm_plain<<<256, 256, 0, stream>>>(Cb, WtD, bd, Hb);

    ln_kernel<<<MM, 256, 0, stream>>>(Hb, pic, lnw, lnb, out);
}